// Round 5
// baseline (238.944 us; speedup 1.0000x reference)
//
#include <hip/hip_runtime.h>
#include <hip/hip_bf16.h>

#define B_ 128
#define D_ 10
#define L_ 1024
#define E_ 300
#define C_ 5
#define NODES 2047
#define HSTR 304   // h / T row stride (300 + 4 zero pad)
#define KP 608     // pair-view K (= 2*HSTR) = 19*32
#define NP 320     // padded N (20 n-tiles of 16)
#define PK 320     // padded K for projection MFMA (10*32)
#define LSTR 328   // tail LDS stride (unchanged, verified)

typedef __attribute__((ext_vector_type(8))) short short8;
typedef __attribute__((ext_vector_type(4))) float f32x4;
typedef __hip_bfloat16 bf16;

__device__ __forceinline__ short f2bs(float v) {
  bf16 b = (bf16)v;
  return *reinterpret_cast<short*>(&b);
}

__device__ __forceinline__ short8 pack_relu(f32x4 v0, f32x4 v1) {
  short8 s;
#pragma unroll
  for (int j = 0; j < 4; j++) s[j] = f2bs(fmaxf(v0[j], 0.f));
#pragma unroll
  for (int j = 0; j < 4; j++) s[4 + j] = f2bs(fmaxf(v1[j], 0.f));
  return s;
}

// ---------------------------------------------------------------------------
// Prep: T[V][304] = bf16(relu(emb)), W_pad[320][608], P_pad[16][320],
//       P_pair[2][16][608]  (all bf16, zero-padded)
// ---------------------------------------------------------------------------
__global__ __launch_bounds__(256) void prep_k(
    const float* __restrict__ emb, const float* __restrict__ Ww,
    const float* __restrict__ Pw, bf16* __restrict__ T, bf16* __restrict__ Wp,
    bf16* __restrict__ Pp, bf16* __restrict__ Pq, int V) {
  int idx = blockIdx.x * 256 + threadIdx.x;
  int tchunks = V * 38;
  if (idx < tchunks) {
    int v = idx / 38, c = idx % 38;
    const float* src = emb + (size_t)v * E_ + c * 8;
    f32x4 v0 = *(const f32x4*)src;
    f32x4 v1;
    if (c == 37) v1 = (f32x4){0.f, 0.f, 0.f, 0.f};
    else v1 = *(const f32x4*)(src + 4);
    *(short8*)(T + (size_t)v * HSTR + c * 8) = pack_relu(v0, v1);
  }
  if (idx < NP * KP) {
    int r = idx / KP, c = idx % KP;
    float v = 0.f;
    if (r < E_) {
      if (c < E_) v = Ww[r * 600 + c];
      else if (c >= HSTR && c < HSTR + E_) v = Ww[r * 600 + (c - 4)];
    }
    Wp[idx] = (bf16)v;
  }
  if (idx < 16 * PK) {
    int r = idx / PK, c = idx % PK;
    float v = (r < C_ && c < E_) ? Pw[r * E_ + c] : 0.f;
    Pp[idx] = (bf16)v;
  }
  if (idx < 2 * 16 * KP) {
    int p = idx / (16 * KP);
    int rem = idx % (16 * KP);
    int r = rem / KP, c = rem % KP;
    int e = c - p * HSTR;
    float v = (r < C_ && e >= 0 && e < E_) ? Pw[r * E_ + e] : 0.f;
    Pq[idx] = (bf16)v;
  }
}

// projection K-fragment load with last-fragment masking (cols 304..319 are
// never written in the [.][304] LDS tile; Pp is zero there, so zero-subst
// is exact and avoids stale-LDS NaN).
#define PROJ_A(rowptr, ks, k0)                                        \
  ((ks) == 9 && half >= 2 ? (short8){0, 0, 0, 0, 0, 0, 0, 0}          \
                          : *(const short8*)((rowptr) + (k0)))

// ---------------------------------------------------------------------------
// Fused level 1: BM=32 pair rows (= 64 leaves) per block, 2048 blocks.
// Wave w: combine cols [80w,80w+80) x 2 row-tiles; leaf-proj row-tile w>>1,
// parity w&1. Depth-2 prefetch on the T gather. Zero main-loop syncs.
// ---------------------------------------------------------------------------
__global__ __launch_bounds__(256, 4) void fused_l1_k(
    const int* __restrict__ wid, const bf16* __restrict__ T,
    const bf16* __restrict__ Wp, const float* __restrict__ Wb,
    const bf16* __restrict__ Pq, const bf16* __restrict__ Pp,
    const float* __restrict__ Pb, bf16* __restrict__ h1,
    float* __restrict__ out) {
  __shared__ bf16 hs[33][HSTR];  // 20.1 KB; row 32 absorbs nothing (guarded)
  int tid = threadIdx.x;
  int w = tid >> 6, l = tid & 63, q = l & 15, half = l >> 4;
  int m0 = blockIdx.x * 32;

  int mr0 = m0 + q, mr1 = m0 + 16 + q;
  int o0a = wid[2 * mr0] * HSTR, o0b = wid[2 * mr0 + 1] * HSTR;
  int o1a = wid[2 * mr1] * HSTR, o1b = wid[2 * mr1 + 1] * HSTR;

  int p = w & 1, rtl = w >> 1;

  f32x4 acc[2][5];
#pragma unroll
  for (int rt = 0; rt < 2; rt++)
#pragma unroll
    for (int nt = 0; nt < 5; nt++) acc[rt][nt] = (f32x4){0.f, 0.f, 0.f, 0.f};
  f32x4 pacc = (f32x4){0.f, 0.f, 0.f, 0.f};

#define LDA(ks, d0, d1)                                          \
  {                                                              \
    int k0_ = (ks) * 32 + half * 8;                              \
    int sel_ = k0_ >= HSTR;                                      \
    int e0_ = sel_ ? k0_ - HSTR : k0_;                           \
    d0 = *(const short8*)(T + (sel_ ? o0b : o0a) + e0_);         \
    d1 = *(const short8*)(T + (sel_ ? o1b : o1a) + e0_);         \
  }

  short8 aA0, aA1, aB0, aB1, aC0, aC1;
  LDA(0, aA0, aA1);
  LDA(1, aB0, aB1);

  for (int ks = 0; ks < 19; ks++) {
    int kn = ks + 2 <= 18 ? ks + 2 : 18;
    LDA(kn, aC0, aC1);
    int k0 = ks * 32 + half * 8;
    // leaf projection: A row-tile rtl (wave-uniform select), parity p
    short8 al = rtl ? aA1 : aA0;
    short8 pqf = *(const short8*)(Pq + ((size_t)p * 16 + q) * KP + k0);
    pacc = __builtin_amdgcn_mfma_f32_16x16x32_bf16(al, pqf, pacc, 0, 0, 0);
#pragma unroll
    for (int nt = 0; nt < 5; nt++) {
      short8 b =
          *(const short8*)(Wp + (size_t)(w * 80 + nt * 16 + q) * KP + k0);
      acc[0][nt] =
          __builtin_amdgcn_mfma_f32_16x16x32_bf16(aA0, b, acc[0][nt], 0, 0, 0);
      acc[1][nt] =
          __builtin_amdgcn_mfma_f32_16x16x32_bf16(aA1, b, acc[1][nt], 0, 0, 0);
    }
    aA0 = aB0; aA1 = aB1;
    aB0 = aC0; aB1 = aC1;
  }
#undef LDA

  // epilogue: bias + relu into LDS (cols < 304 only; 300-303 are exact zeros)
#pragma unroll
  for (int nt = 0; nt < 5; nt++) {
    int n = w * 80 + nt * 16 + q;
    float wb = (n < E_) ? Wb[n] : 0.f;
    if (n < HSTR) {
#pragma unroll
      for (int rt = 0; rt < 2; rt++)
#pragma unroll
        for (int j = 0; j < 4; j++) {
          int rl = rt * 16 + half * 4 + j;
          hs[rl][n] = (bf16)fmaxf(acc[rt][nt][j] + wb, 0.f);
        }
    }
  }
  // leaf logit stores (register-resident)
  if (q < C_) {
    float pb = Pb[q];
#pragma unroll
    for (int j = 0; j < 4; j++) {
      int leaf = 2 * (m0 + rtl * 16 + half * 4 + j) + p;
      out[((size_t)(leaf >> 10) * NODES + (leaf & 1023)) * C_ + q] =
          pacc[j] + pb;
    }
  }
  __syncthreads();

  // cooperative h1 store
  for (int i = tid; i < 32 * 38; i += 256) {
    int r = i / 38, c = i % 38;
    *(short8*)(h1 + (size_t)(m0 + r) * HSTR + c * 8) =
        *(const short8*)&hs[r][c * 8];
  }
  // L1 projection: waves 0,1 rows [16w,16w+16)
  if (w < 2) {
    f32x4 pc = (f32x4){0.f, 0.f, 0.f, 0.f};
#pragma unroll
    for (int ks = 0; ks < 10; ks++) {
      int k0 = ks * 32 + half * 8;
      short8 a = PROJ_A(&hs[w * 16 + q][0], ks, k0);
      short8 b = *(const short8*)(Pp + (size_t)q * PK + k0);
      pc = __builtin_amdgcn_mfma_f32_16x16x32_bf16(a, b, pc, 0, 0, 0);
    }
    if (q < C_) {
      float pb = Pb[q];
#pragma unroll
      for (int j = 0; j < 4; j++) {
        int m = m0 + w * 16 + half * 4 + j;
        out[((size_t)(m >> 9) * NODES + 1024 + (m & 511)) * C_ + q] =
            pc[j] + pb;
      }
    }
  }
}

// ---------------------------------------------------------------------------
// Combine levels 2..5. RT row-tiles (BM = 16*RT), 4 waves; A from global.
// ---------------------------------------------------------------------------
template <int RT>
__global__ __launch_bounds__(256, 4) void combine_k(
    const bf16* __restrict__ h_in, const bf16* __restrict__ Wp,
    const float* __restrict__ Wb, const bf16* __restrict__ Pp,
    const float* __restrict__ Pb, bf16* __restrict__ h_out,
    float* __restrict__ out, int node_off, int nshift) {
  __shared__ bf16 hs[RT * 16 + 1][HSTR];
  int tid = threadIdx.x;
  int w = tid >> 6, l = tid & 63, q = l & 15, half = l >> 4;
  size_t m0 = (size_t)blockIdx.x * (RT * 16);

  f32x4 acc[RT][5];
#pragma unroll
  for (int rt = 0; rt < RT; rt++)
#pragma unroll
    for (int nt = 0; nt < 5; nt++) acc[rt][nt] = (f32x4){0.f, 0.f, 0.f, 0.f};

  for (int ks = 0; ks < 19; ks++) {
    int k0 = ks * 32 + half * 8;
    short8 a[RT];
#pragma unroll
    for (int rt = 0; rt < RT; rt++)
      a[rt] = *(const short8*)(h_in + (m0 + rt * 16 + q) * KP + k0);
#pragma unroll
    for (int nt = 0; nt < 5; nt++) {
      short8 b =
          *(const short8*)(Wp + (size_t)(w * 80 + nt * 16 + q) * KP + k0);
#pragma unroll
      for (int rt = 0; rt < RT; rt++)
        acc[rt][nt] = __builtin_amdgcn_mfma_f32_16x16x32_bf16(a[rt], b,
                                                              acc[rt][nt], 0,
                                                              0, 0);
    }
  }

#pragma unroll
  for (int nt = 0; nt < 5; nt++) {
    int n = w * 80 + nt * 16 + q;
    float wb = (n < E_) ? Wb[n] : 0.f;
    if (n < HSTR) {
#pragma unroll
      for (int rt = 0; rt < RT; rt++)
#pragma unroll
        for (int j = 0; j < 4; j++) {
          int rl = rt * 16 + half * 4 + j;
          hs[rl][n] = (bf16)fmaxf(acc[rt][nt][j] + wb, 0.f);
        }
    }
  }
  __syncthreads();

  for (int i = tid; i < RT * 16 * 38; i += 256) {
    int r = i / 38, c = i % 38;
    *(short8*)(h_out + (m0 + r) * HSTR + c * 8) = *(const short8*)&hs[r][c * 8];
  }

  if (w < RT) {
    f32x4 pacc = (f32x4){0.f, 0.f, 0.f, 0.f};
#pragma unroll
    for (int ks = 0; ks < 10; ks++) {
      int k0 = ks * 32 + half * 8;
      short8 a = PROJ_A(&hs[16 * w + q][0], ks, k0);
      short8 b = *(const short8*)(Pp + (size_t)q * PK + k0);
      pacc = __builtin_amdgcn_mfma_f32_16x16x32_bf16(a, b, pacc, 0, 0, 0);
    }
    if (q < C_) {
      float pb = Pb[q];
#pragma unroll
      for (int j = 0; j < 4; j++) {
        size_t m = m0 + w * 16 + half * 4 + j;
        size_t b_ = m >> nshift;
        size_t n = m & (((size_t)1 << nshift) - 1);
        out[((size_t)b_ * NODES + node_off + n) * C_ + q] = pacc[j] + pb;
      }
    }
  }
}

// ---------------------------------------------------------------------------
// Tail: levels 6..10, one tree per block (input h5[b]: 32 rows).
// ---------------------------------------------------------------------------
__global__ __launch_bounds__(256) void tail_k(
    const bf16* __restrict__ h5, const bf16* __restrict__ Wp,
    const float* __restrict__ Wb, const bf16* __restrict__ Pp,
    const float* __restrict__ Pb, float* __restrict__ out) {
  __shared__ bf16 bufs[2][32][LSTR];
  int tid = threadIdx.x, b = blockIdx.x;
  int w = tid >> 6, l = tid & 63, q = l & 15, half = l >> 4;

  for (int i = tid; i < 32 * 38; i += 256) {
    int r = i / 38, c = i % 38;
    *(short8*)&bufs[0][r][c * 8] =
        *(const short8*)(h5 + ((size_t)b * 32 + r) * HSTR + c * 8);
  }
  __syncthreads();

  int p = 0, off = 2016, Mo = 16;
  for (int lev = 0; lev < 5; lev++) {
    f32x4 acc[5];
#pragma unroll
    for (int t = 0; t < 5; t++) acc[t] = (f32x4){0.f, 0.f, 0.f, 0.f};
    for (int ks = 0; ks < 19; ks++) {
      int k0 = ks * 32 + half * 8;
      int sel = k0 >= HSTR;
      int e0 = k0 - (sel ? HSTR : 0);
      short8 a = *(const short8*)&bufs[p][2 * q + sel][e0];
#pragma unroll
      for (int t = 0; t < 5; t++) {
        int nt = w + 4 * t;
        short8 bfr = *(const short8*)(Wp + ((size_t)nt * 16 + q) * KP + k0);
        acc[t] =
            __builtin_amdgcn_mfma_f32_16x16x32_bf16(a, bfr, acc[t], 0, 0, 0);
      }
    }
    __syncthreads();
#pragma unroll
    for (int t = 0; t < 5; t++) {
      int nt = w + 4 * t;
      int n = nt * 16 + q;
      float wb = (n < E_) ? Wb[n] : 0.f;
#pragma unroll
      for (int j = 0; j < 4; j++) {
        int r = half * 4 + j;
        bufs[p ^ 1][r][n] = (bf16)fmaxf(acc[t][j] + wb, 0.f);
      }
    }
    __syncthreads();
    if (w == 0) {
      f32x4 pc = (f32x4){0.f, 0.f, 0.f, 0.f};
#pragma unroll
      for (int ks = 0; ks < 10; ks++) {
        int k0 = ks * 32 + half * 8;
        short8 a = *(const short8*)&bufs[p ^ 1][q][k0];
        short8 bfr = *(const short8*)(Pp + (size_t)q * PK + k0);
        pc = __builtin_amdgcn_mfma_f32_16x16x32_bf16(a, bfr, pc, 0, 0, 0);
      }
      if (q < C_) {
        float pb = Pb[q];
#pragma unroll
        for (int j = 0; j < 4; j++) {
          int r = half * 4 + j;
          if (r < Mo) out[((size_t)b * NODES + off + r) * C_ + q] = pc[j] + pb;
        }
      }
    }
    p ^= 1;
    off += Mo;
    Mo >>= 1;
  }
}

// ---------------------------------------------------------------------------
extern "C" void kernel_launch(void* const* d_in, const int* in_sizes, int n_in,
                              void* d_out, int out_size, void* d_ws,
                              size_t ws_size, hipStream_t stream) {
  const int* wid = (const int*)d_in[0];
  const float* emb = (const float*)d_in[1];
  const float* Ww = (const float*)d_in[2];
  const float* Wb = (const float*)d_in[3];
  const float* Pw = (const float*)d_in[4];
  const float* Pb = (const float*)d_in[5];
  float* out = (float*)d_out;
  int V = in_sizes[1] / E_;  // 50000

  bf16* hA = (bf16*)d_ws;                    // h1, h3, h5
  bf16* hB = hA + (size_t)B_ * 512 * HSTR;   // h2, h4
  bf16* Wp = hB + (size_t)B_ * 256 * HSTR;
  bf16* Pp = Wp + (size_t)NP * KP;
  bf16* Pq = Pp + (size_t)16 * PK;
  bf16* T = Pq + (size_t)2 * 16 * KP;        // V * 304

  int tchunks = V * 38;
  prep_k<<<(tchunks + 255) / 256, 256, 0, stream>>>(emb, Ww, Pw, T, Wp, Pp, Pq,
                                                    V);
  fused_l1_k<<<(B_ * 512) / 32, 256, 0, stream>>>(wid, T, Wp, Wb, Pq, Pp, Pb,
                                                  hA, out);
  // lvl2: 32768 rows, BM=32
  combine_k<2><<<1024, 256, 0, stream>>>(hA, Wp, Wb, Pp, Pb, hB, out, 1536, 8);
  // lvl3: 16384 rows, BM=32
  combine_k<2><<<512, 256, 0, stream>>>(hB, Wp, Wb, Pp, Pb, hA, out, 1792, 7);
  // lvl4: 8192 rows, BM=16
  combine_k<1><<<512, 256, 0, stream>>>(hA, Wp, Wb, Pp, Pb, hB, out, 1920, 6);
  // lvl5: 4096 rows, BM=16
  combine_k<1><<<256, 256, 0, stream>>>(hB, Wp, Wb, Pp, Pb, hA, out, 1984, 5);
  tail_k<<<B_, 256, 0, stream>>>(hA, Wp, Wb, Pp, Pb, out);
}